// Round 2
// baseline (622.449 us; speedup 1.0000x reference)
//
#include <hip/hip_runtime.h>
#include <math.h>

#define C_IN 32
#define C2C 64
#define HH 256
#define WW 256

// A&S 7.1.26 erf approximation, |err| <= 1.5e-7; branchless, ~14 VALU.
__device__ __forceinline__ float fast_gelu(float x) {
    float q = 0.70710678118654752f * x;
    float a = fabsf(q);
    float t = __builtin_amdgcn_rcpf(1.0f + 0.3275911f * a);
    float p = t * (0.254829592f + t * (-0.284496736f +
              t * (1.421413741f + t * (-1.453152027f + t * 1.061405429f))));
    float e = __expf(-q * q);
    float er = 1.0f - p * e;
    er = copysignf(er, q);
    return 0.5f * x * (1.0f + er);
}

// cos/sin(2*pi*k/8)
__device__ const float CT8[8] = {1.0f, 0.70710678118654752f, 0.0f, -0.70710678118654752f,
                                 -1.0f, -0.70710678118654752f, 0.0f, 0.70710678118654752f};
__device__ const float ST8[8] = {0.0f, 0.70710678118654752f, 1.0f, 0.70710678118654752f,
                                 0.0f, -0.70710678118654752f, -1.0f, -0.70710678118654752f};

// ---------------------------------------------------------------------------
// K1: wave-synchronous spectral pipeline. Block = 512 thr = 8 waves = 1 patch.
// Each wave loops 8 c2 jobs; lane = pixel (h = lane>>3, w = lane&7).
// Conv reads: 8 ds_read_b128/job from XOR-swizzled xs[px][c]; weights scalar.
// DFT/transposes: ds_bpermute only. No barriers after staging.
// ---------------------------------------------------------------------------
__global__ __launch_bounds__(512)
void k1_spectral(const float* __restrict__ x, const float* __restrict__ w_in,
                 const float* __restrict__ b_in, const float* __restrict__ fft1,
                 const float* __restrict__ fft2, float* __restrict__ z)
{
    __shared__ __align__(16) float xs[2048];   // [px][32c], c-blocks XOR-swizzled by px&7

    const int tid = threadIdx.x;
    const int wp = blockIdx.x, hp = blockIdx.y, b = blockIdx.z;
    const int h0 = hp * 8, w0 = wp * 8;

    // ---- stage x: 2048 floats, swizzled so conv b128 reads are conflict-free ----
    #pragma unroll
    for (int k = 0; k < 4; ++k) {
        int i = tid + k * 512;
        int c = i >> 6, px = i & 63;
        float v = x[((b * C_IN + c) * HH + h0 + (px >> 3)) * WW + w0 + (px & 7)];
        xs[px * 32 + (((c >> 2) ^ (px & 7)) << 2) + (c & 3)] = v;
    }
    __syncthreads();

    const int lane = tid & 63;
    const int wv   = tid >> 6;
    const int uu   = lane >> 3;   // role: h (fwd) / u / h' (inv)
    const int ww   = lane & 7;    // role: w (fwd) / v / w' (inv)

    // ---- per-lane twiddle registers (loaded once) ----
    float cu[8], su[8], cv[8], sv[8];
    #pragma unroll
    for (int j = 0; j < 8; ++j) {
        cu[j] = CT8[(uu * j) & 7]; su[j] = ST8[(uu * j) & 7];
        cv[j] = CT8[(ww * j) & 7]; sv[j] = ST8[(ww * j) & 7];
    }
    // bpermute byte indices: idxH[j] -> lane (j, ww) [stride-8 group], idxW[j] -> lane (uu, j)
    int idxH[8], idxW[8];
    #pragma unroll
    for (int j = 0; j < 8; ++j) {
        idxH[j] = (ww + 8 * j) << 2;
        idxW[j] = ((uu << 3) + j) << 2;
    }
    const int   s    = ww;                         // conv swizzle key = px&7
    const float mvs  = ((ww == 0) || (ww == 4)) ? 0.015625f : 0.03125f;  // m_v / 64
    const int   vcl  = (ww < 4) ? ww : 4;          // clamp v for filter load
    const float4* xs4 = (const float4*)xs;
    const int   xbase = lane * 8;                  // float4 units

    for (int j = 0; j < 8; ++j) {
        const int c2u = __builtin_amdgcn_readfirstlane(wv * 8 + j);

        // ---- 1x1 conv: t(h,w) for channel c2u; scalar weights ----
        float t = b_in[c2u];
        #pragma unroll
        for (int k = 0; k < 8; ++k) {
            float4 xv = xs4[xbase + (k ^ s)];
            const float* wr = &w_in[c2u * 32 + 4 * k];
            t += wr[0] * xv.x + wr[1] * xv.y + wr[2] * xv.z + wr[3] * xv.w;
        }

        // ---- row DFT over h (e^{-i}): lane holds A(u=uu, w=ww) ----
        float Ar = 0.f, Ai = 0.f;
        {
            int ti = __float_as_int(t);
            #pragma unroll
            for (int jj = 0; jj < 8; ++jj) {
                float tj = __int_as_float(__builtin_amdgcn_ds_bpermute(idxH[jj], ti));
                Ar += tj * cu[jj];
                Ai -= tj * su[jj];
            }
        }

        // ---- col DFT over w (e^{-i}): lane holds F(u=uu, v=ww), valid v<=4 ----
        float Fr = 0.f, Fi = 0.f;
        {
            int Ari = __float_as_int(Ar), Aii = __float_as_int(Ai);
            #pragma unroll
            for (int jj = 0; jj < 8; ++jj) {
                float ar = __int_as_float(__builtin_amdgcn_ds_bpermute(idxW[jj], Ari));
                float ai = __int_as_float(__builtin_amdgcn_ds_bpermute(idxW[jj], Aii));
                Fr += ar * cv[jj] + ai * sv[jj];
                Fi += ai * cv[jj] - ar * sv[jj];
            }
        }

        // ---- * fft1 -> gelu -> * (fft2 * m_v / 64) ----
        const int fidx = (c2u * 8 + uu) * 5 + vcl;
        float s1 = fft1[fidx];
        float s2 = fft2[fidx] * mvs;
        float gr = fast_gelu(Fr * s1) * s2;
        float gi = fast_gelu(Fi * s1) * s2;

        // ---- inverse stage 1 over v=0..4 (e^{+i}): P(u, w'=ww) ----
        float Pr = 0.f, Pi = 0.f;
        {
            int gri = __float_as_int(gr), gii = __float_as_int(gi);
            #pragma unroll
            for (int v = 0; v < 5; ++v) {
                float gvr = __int_as_float(__builtin_amdgcn_ds_bpermute(idxW[v], gri));
                float gvi = __int_as_float(__builtin_amdgcn_ds_bpermute(idxW[v], gii));
                Pr += gvr * cv[v] - gvi * sv[v];
                Pi += gvr * sv[v] + gvi * cv[v];
            }
        }

        // ---- inverse stage 2 over u (e^{+i}, take Re): z(h'=uu, w'=ww) ----
        float zv = 0.f;
        {
            int Pri = __float_as_int(Pr), Pii = __float_as_int(Pi);
            #pragma unroll
            for (int jj = 0; jj < 8; ++jj) {
                float pr = __int_as_float(__builtin_amdgcn_ds_bpermute(idxH[jj], Pri));
                float pi = __int_as_float(__builtin_amdgcn_ds_bpermute(idxH[jj], Pii));
                zv += pr * cu[jj] - pi * su[jj];
            }
        }
        z[((b * C2C + c2u) * HH + h0 + uu) * WW + w0 + ww] = zv;
    }
}

// ---------------------------------------------------------------------------
// K2: 7x7 depthwise + gelu + 1x1 out. 16x16 tile / 256 thr. 4 chunks x 16 ch.
// Conv phase: lane = (x in 0..15, c2l in 0..3); each lane computes a full
// 16-row column via branchless 22-row unroll (exactly 49 FMA/px), weights in
// VGPRs, ds_read offsets all immediate. Fold: 4 aligned b128 gbuf reads,
// w_out scalar.
// ---------------------------------------------------------------------------
__global__ __launch_bounds__(256)
void k2_dwconv(const float* __restrict__ z, const float* __restrict__ w_dw,
               const float* __restrict__ b_dw, const float* __restrict__ w_out,
               const float* __restrict__ b_out, float* __restrict__ out)
{
    __shared__ float zs[16 * 506];                 // 16 ch x 22 rows x stride 23 = 32384 B
    __shared__ __align__(16) float gbuf[256 * 20]; // [px][20] (16 ch + pad)  = 20480 B

    const int tid = threadIdx.x;
    const int tx = blockIdx.x, ty = blockIdx.y, b = blockIdx.z;
    const int x0g = tx * 16, y0g = ty * 16;

    const int lane = tid & 63;
    const int wv   = tid >> 6;
    const int lx   = lane & 15;     // x within tile
    const int lc   = lane >> 4;     // c2l within wave
    const int ch   = wv * 4 + lc;   // channel-in-chunk 0..15
    const int ox = tid & 15, oy = tid >> 4;

    float acc[32];
    #pragma unroll
    for (int c = 0; c < 32; ++c) acc[c] = b_out[c];

    for (int chunk = 0; chunk < 4; ++chunk) {
        __syncthreads();   // gbuf readers (prev fold) + zs readers done
        // ---- stage 16 channels, 22x22 halo, zero-padded ----
        for (int i = tid; i < 16 * 22 * 22; i += 256) {
            int c2l = i / 484;
            int r   = i - c2l * 484;
            int yy  = r / 22;
            int xx  = r - yy * 22;
            int gy = y0g - 3 + yy, gx = x0g - 3 + xx;
            float v = 0.f;
            if ((unsigned)gy < HH && (unsigned)gx < WW)
                v = z[((b * C2C + chunk * 16 + c2l) * HH + gy) * WW + gx];
            zs[c2l * 506 + yy * 23 + xx] = v;
        }
        __syncthreads();

        // ---- depthwise 7x7 for channel c2, full 16-row column per lane ----
        const int c2 = chunk * 16 + ch;
        float wk[49];
        #pragma unroll
        for (int j = 0; j < 49; ++j) wk[j] = w_dw[c2 * 49 + j];
        float a16[16];
        {
            float bd = b_dw[c2];
            #pragma unroll
            for (int y = 0; y < 16; ++y) a16[y] = bd;
        }
        const float* zrow = &zs[ch * 506 + lx];
        #pragma unroll
        for (int r = 0; r < 22; ++r) {
            float v[7];
            #pragma unroll
            for (int kx = 0; kx < 7; ++kx) v[kx] = zrow[r * 23 + kx];
            const int ylo = (r - 6 > 0) ? (r - 6) : 0;
            const int yhi = (r < 15) ? r : 15;
            #pragma unroll
            for (int y = ylo; y <= yhi; ++y) {
                const int ky = r - y;           // compile-time after unroll
                float sacc = 0.f;
                #pragma unroll
                for (int kx = 0; kx < 7; ++kx) sacc += wk[ky * 7 + kx] * v[kx];
                a16[y] += sacc;
            }
        }
        // ---- gelu -> gbuf (stride-20, 2-way-max banks) ----
        #pragma unroll
        for (int y = 0; y < 16; ++y)
            gbuf[(y * 16 + lx) * 20 + ch] = fast_gelu(a16[y]);
        __syncthreads();

        // ---- fold 16 channels into 32 output accumulators (w_out scalar) ----
        float gv[16];
        {
            const float4* g4 = (const float4*)&gbuf[(oy * 16 + ox) * 20];
            #pragma unroll
            for (int k = 0; k < 4; ++k) {
                float4 q = g4[k];
                gv[4 * k] = q.x; gv[4 * k + 1] = q.y; gv[4 * k + 2] = q.z; gv[4 * k + 3] = q.w;
            }
        }
        #pragma unroll
        for (int cc = 0; cc < 16; ++cc) {
            #pragma unroll
            for (int c = 0; c < 32; ++c)
                acc[c] += w_out[c * C2C + chunk * 16 + cc] * gv[cc];
        }
    }

    #pragma unroll
    for (int c = 0; c < 32; ++c)
        out[((b * C_IN + c) * HH + y0g + oy) * WW + x0g + ox] = acc[c];
}

extern "C" void kernel_launch(void* const* d_in, const int* in_sizes, int n_in,
                              void* d_out, int out_size, void* d_ws, size_t ws_size,
                              hipStream_t stream) {
    const float* x     = (const float*)d_in[0];
    const float* w_in  = (const float*)d_in[1];
    const float* b_in  = (const float*)d_in[2];
    const float* fft1  = (const float*)d_in[3];
    const float* fft2  = (const float*)d_in[4];
    const float* w_dw  = (const float*)d_in[5];
    const float* b_dw  = (const float*)d_in[6];
    const float* w_out = (const float*)d_in[7];
    const float* b_out = (const float*)d_in[8];
    float* outp = (float*)d_out;
    float* z = (float*)d_ws;   // 8*64*256*256 fp32 = 128 MiB intermediate

    dim3 g1(32, 32, 8);
    k1_spectral<<<g1, 512, 0, stream>>>(x, w_in, b_in, fft1, fft2, z);
    dim3 g2(16, 16, 8);
    k2_dwconv<<<g2, 256, 0, stream>>>(z, w_dw, b_dw, w_out, b_out, outp);
}

// Round 3
// 559.988 us; speedup vs baseline: 1.1115x; 1.1115x over previous
//
#include <hip/hip_runtime.h>
#include <math.h>

#define C_IN 32
#define C2C 64
#define HH 256
#define WW 256

// A&S 7.1.26 erf approximation, |err| <= 1.5e-7; branchless.
__device__ __forceinline__ float fast_gelu(float x) {
    float q = 0.70710678118654752f * x;
    float a = fabsf(q);
    float t = __builtin_amdgcn_rcpf(1.0f + 0.3275911f * a);
    float p = t * (0.254829592f + t * (-0.284496736f +
              t * (1.421413741f + t * (-1.453152027f + t * 1.061405429f))));
    float e = __expf(-q * q);
    float er = 1.0f - p * e;
    er = copysignf(er, q);
    return 0.5f * x * (1.0f + er);
}

// cos/sin(2*pi*k/8) for runtime-index lookups (phase C twiddles)
__device__ const float CT8g[8] = {1.0f, 0.70710678118654752f, 0.0f, -0.70710678118654752f,
                                  -1.0f, -0.70710678118654752f, 0.0f, 0.70710678118654752f};
__device__ const float ST8g[8] = {0.0f, 0.70710678118654752f, 1.0f, 0.70710678118654752f,
                                  0.0f, -0.70710678118654752f, -1.0f, -0.70710678118654752f};

// ---------------------------------------------------------------------------
// K1: 1x1 conv (32->64) + per-8x8-patch rfft2*fft1 -> gelu -> *fft2 -> irfft2
// Block = 512 thr = 8 waves = 1 patch. ONE barrier (after x staging).
// Wave w handles channels c2 = 8w..8w+7. All DFT twiddles are literal
// constants except phase-C's runtime-h lookup (16 rodata loads, once).
// All post-staging LDS traffic is wave-private (in-order LDS pipe => no sync).
// ---------------------------------------------------------------------------
__global__ __launch_bounds__(512, 2)
void k1_spectral(const float* __restrict__ x, const float* __restrict__ w_in,
                 const float* __restrict__ b_in, const float* __restrict__ fft1,
                 const float* __restrict__ fft2, float* __restrict__ z)
{
    constexpr float CT[8] = {1.0f, 0.70710678118654752f, 0.0f, -0.70710678118654752f,
                             -1.0f, -0.70710678118654752f, 0.0f, 0.70710678118654752f};
    constexpr float ST[8] = {0.0f, 0.70710678118654752f, 1.0f, 0.70710678118654752f,
                             0.0f, -0.70710678118654752f, -1.0f, -0.70710678118654752f};

    __shared__ __align__(16) float xs[2048];      // [px][32c], c-blocks XOR-swizzled by px&7
    __shared__ __align__(16) float Tb[8 * 544];   // per-wave: [j][w*8+h], stride 68
    __shared__ __align__(16) float Ab[8 * 800];   // per-wave: [c2l][w][10+2pad], strides 100/12
    __shared__ __align__(16) float Gb[8 * 672];   // per-wave: [c2l][v][u-float2], strides 84/16

    const int tid = threadIdx.x;
    const int wp = blockIdx.x, hp_ = blockIdx.y, b = blockIdx.z;
    const int h0 = hp_ * 8, w0 = wp * 8;

    // ---- stage x: each thread loads one float4 (w-contiguous), scatters 4 b32 ----
    {
        const int c  = tid >> 4;
        const int h  = (tid >> 1) & 7;
        const int w4 = tid & 1;
        float4 xv = *(const float4*)&x[((b * C_IN + c) * HH + h0 + h) * WW + w0 + 4 * w4];
        const int cb = c >> 2, ce = c & 3;
        const float vv[4] = {xv.x, xv.y, xv.z, xv.w};
        #pragma unroll
        for (int d = 0; d < 4; ++d) {
            int px = h * 8 + 4 * w4 + d;
            xs[px * 32 + (((cb ^ (px & 7)) << 2) + ce)] = vv[d];
        }
    }
    __syncthreads();

    const int lane = tid & 63;
    const int wv   = tid >> 6;

    // ================= Phase A: lane = pixel (h=lane>>3, w=lane&7) ============
    const int s = lane & 7;
    float4 xr[8];
    #pragma unroll
    for (int cb = 0; cb < 8; ++cb)
        xr[cb] = *(const float4*)&xs[(lane << 5) + ((cb ^ s) << 2)];

    float t[8];
    #pragma unroll
    for (int j = 0; j < 8; ++j) {
        const int c2u = __builtin_amdgcn_readfirstlane(wv * 8 + j);
        float a = b_in[c2u];
        #pragma unroll
        for (int cb = 0; cb < 8; ++cb) {
            const float* wr = &w_in[c2u * 32 + 4 * cb];
            a += wr[0] * xr[cb].x + wr[1] * xr[cb].y + wr[2] * xr[cb].z + wr[3] * xr[cb].w;
        }
        t[j] = a;
    }

    // remap t -> lane-as-(channel, column): write T[j][w][h]
    float* Tw = &Tb[wv * 544];
    {
        const int h_p = lane >> 3, w_p = lane & 7;
        #pragma unroll
        for (int j = 0; j < 8; ++j)
            Tw[j * 68 + w_p * 8 + h_p] = t[j];
    }

    // ================= Phase B: lane = (c2l = lane>>3, wq = lane&7) ===========
    const int c2l = lane >> 3, wq = lane & 7;

    float tc[8];
    {
        float4 q0 = *(const float4*)&Tw[c2l * 68 + wq * 8];
        float4 q1 = *(const float4*)&Tw[c2l * 68 + wq * 8 + 4];
        tc[0] = q0.x; tc[1] = q0.y; tc[2] = q0.z; tc[3] = q0.w;
        tc[4] = q1.x; tc[5] = q1.y; tc[6] = q1.z; tc[7] = q1.w;
    }

    // row DFT over h, u = 0..4 only (A(8-u) = conj(A(u)) for real input)
    float Ar[5], Ai[5];
    #pragma unroll
    for (int u = 0; u <= 4; ++u) {
        float sr = 0.f, si = 0.f;
        #pragma unroll
        for (int h = 0; h < 8; ++h) {
            const int k = (u * h) & 7;
            sr += tc[h] * CT[k];
            si -= tc[h] * ST[k];
        }
        Ar[u] = sr; Ai[u] = si;
    }
    float* Awp = &Ab[wv * 800 + c2l * 100 + wq * 12];
    *(float4*)Awp       = make_float4(Ar[0], Ai[0], Ar[1], Ai[1]);
    *(float4*)(Awp + 4) = make_float4(Ar[2], Ai[2], Ar[3], Ai[3]);
    *(float2*)(Awp + 8) = make_float2(Ar[4], Ai[4]);

    // col DFT: lane role u' = wq, outputs F(u', v=0..4)
    const int up   = wq;
    const int uidx = (up <= 4) ? up : 8 - up;
    const float csn = (up <= 4) ? 1.0f : -1.0f;
    float Awr[8], Awi[8];
    {
        const float* Arow = &Ab[wv * 800 + c2l * 100];
        #pragma unroll
        for (int w = 0; w < 8; ++w) {
            float2 a2 = *(const float2*)&Arow[w * 12 + 2 * uidx];
            Awr[w] = a2.x; Awi[w] = csn * a2.y;
        }
    }

    const int fb = ((wv * 8 + c2l) * 8 + up) * 5;
    float gr[5], gi[5];
    #pragma unroll
    for (int v = 0; v <= 4; ++v) {
        float Fr = 0.f, Fi = 0.f;
        #pragma unroll
        for (int w = 0; w < 8; ++w) {
            const int k = (v * w) & 7;
            Fr += Awr[w] * CT[k] + Awi[w] * ST[k];
            Fi += Awi[w] * CT[k] - Awr[w] * ST[k];
        }
        float s1 = fft1[fb + v];
        float mv = (v == 0 || v == 4) ? 0.015625f : 0.03125f;   // m_v / 64
        float s2 = fft2[fb + v] * mv;
        gr[v] = fast_gelu(Fr * s1) * s2;
        gi[v] = fast_gelu(Fi * s1) * s2;
    }

    float* Gw = &Gb[wv * 672 + c2l * 84];
    #pragma unroll
    for (int v = 0; v <= 4; ++v)
        *(float2*)&Gw[v * 16 + 2 * up] = make_float2(gr[v], gi[v]);

    // ================= Phase C: lane role h' = wq ============================
    const int hq = wq;
    float chh[8], shh[8];
    #pragma unroll
    for (int u = 0; u < 8; ++u) {
        const int k = (u * hq) & 7;
        chh[u] = CT8g[k]; shh[u] = ST8g[k];
    }

    float Rr[5], Ri[5];
    #pragma unroll
    for (int v = 0; v <= 4; ++v) {
        float4 g0 = *(const float4*)&Gw[v * 16];
        float4 g1 = *(const float4*)&Gw[v * 16 + 4];
        float4 g2 = *(const float4*)&Gw[v * 16 + 8];
        float4 g3 = *(const float4*)&Gw[v * 16 + 12];
        float rr, ri;
        rr  = g0.x * chh[0] - g0.y * shh[0];  ri  = g0.x * shh[0] + g0.y * chh[0];
        rr += g0.z * chh[1] - g0.w * shh[1];  ri += g0.z * shh[1] + g0.w * chh[1];
        rr += g1.x * chh[2] - g1.y * shh[2];  ri += g1.x * shh[2] + g1.y * chh[2];
        rr += g1.z * chh[3] - g1.w * shh[3];  ri += g1.z * shh[3] + g1.w * chh[3];
        rr += g2.x * chh[4] - g2.y * shh[4];  ri += g2.x * shh[4] + g2.y * chh[4];
        rr += g2.z * chh[5] - g2.w * shh[5];  ri += g2.z * shh[5] + g2.w * chh[5];
        rr += g3.x * chh[6] - g3.y * shh[6];  ri += g3.x * shh[6] + g3.y * chh[6];
        rr += g3.z * chh[7] - g3.w * shh[7];  ri += g3.z * shh[7] + g3.w * chh[7];
        Rr[v] = rr; Ri[v] = ri;
    }

    float zr[8];
    #pragma unroll
    for (int w = 0; w < 8; ++w) {
        float acc = 0.f;
        #pragma unroll
        for (int v = 0; v <= 4; ++v) {
            const int k = (v * w) & 7;
            acc += Rr[v] * CT[k] - Ri[v] * ST[k];
        }
        zr[w] = acc;
    }
    float* zp = &z[((b * C2C + wv * 8 + c2l) * HH + h0 + hq) * WW + w0];
    *(float4*)zp       = make_float4(zr[0], zr[1], zr[2], zr[3]);
    *(float4*)(zp + 4) = make_float4(zr[4], zr[5], zr[6], zr[7]);
}

// ---------------------------------------------------------------------------
// K2: 7x7 depthwise conv (pad 3) + gelu + 1x1 conv out (64->32).
// 16x16 tile / 256 thr, 4 chunks x 16 channels.
// Conv thread = (x-quad 0..3, 4-row band 0..3, ch 0..15): exactly 49 FMA/px,
// 30 aligned ds_read_b128 per chunk, dw weights in VGPRs (L1-hot global).
// Fold thread = pixel: acc[32] persists, w_out via scalar loads.
// ---------------------------------------------------------------------------
__global__ __launch_bounds__(256, 2)
void k2_dwconv(const float* __restrict__ z, const float* __restrict__ w_dw,
               const float* __restrict__ b_dw, const float* __restrict__ w_out,
               const float* __restrict__ b_out, float* __restrict__ out)
{
    __shared__ __align__(16) float zs[16 * 620];    // [ch][22 rows][28 stride] 39.7 KB
    __shared__ __align__(16) float gbuf[16 * 324];  // [ch][16 rows][20 stride] 20.7 KB

    const int tid = threadIdx.x;
    const int tx = blockIdx.x, ty = blockIdx.y, b = blockIdx.z;
    const int x0g = tx * 16, y0g = ty * 16;

    // conv-phase roles
    const int xq = tid & 3;          // x-quad (4 px)
    const int ys = (tid >> 2) & 3;   // 4-row band
    const int ch = tid >> 4;         // channel in chunk, 0..15
    // fold-phase roles
    const int ox = tid & 15, oy = tid >> 4;

    float acc[32];
    #pragma unroll
    for (int c = 0; c < 32; ++c) acc[c] = b_out[c];

    for (int cc = 0; cc < 4; ++cc) {
        __syncthreads();   // prev-iter zs/gbuf readers done
        // ---- stage 16 channels, 22x22 halo, zero-padded ----
        for (int i = tid; i < 16 * 484; i += 256) {
            int c2l = i / 484;
            int r   = i - c2l * 484;
            int yy  = r / 22;
            int xx  = r - yy * 22;
            int gy = y0g - 3 + yy, gx = x0g - 3 + xx;
            float v = 0.f;
            if ((unsigned)gy < HH && (unsigned)gx < WW)
                v = z[((b * C2C + cc * 16 + c2l) * HH + gy) * WW + gx];
            zs[c2l * 620 + yy * 28 + xx] = v;
        }
        __syncthreads();

        // ---- depthwise 7x7: 4x4 px per thread, exactly 49 FMA/px ----
        const int c2 = cc * 16 + ch;
        float wk[49];
        #pragma unroll
        for (int j = 0; j < 49; ++j) wk[j] = w_dw[c2 * 49 + j];
        float a[4][4];
        #pragma unroll
        for (int i = 0; i < 4; ++i)
            #pragma unroll
            for (int d = 0; d < 4; ++d) a[i][d] = 0.f;

        const float* zbase = &zs[ch * 620 + 4 * xq];
        #pragma unroll
        for (int ry = 0; ry < 10; ++ry) {
            const int r = ys * 4 + ry;
            float4 q0 = *(const float4*)&zbase[r * 28];
            float4 q1 = *(const float4*)&zbase[r * 28 + 4];
            float4 q2 = *(const float4*)&zbase[r * 28 + 8];
            const float row[12] = {q0.x,q0.y,q0.z,q0.w, q1.x,q1.y,q1.z,q1.w,
                                   q2.x,q2.y,q2.z,q2.w};
            const int olo = (ry - 6 > 0) ? (ry - 6) : 0;
            const int ohi = (ry < 3) ? ry : 3;
            #pragma unroll
            for (int oyi = olo; oyi <= ohi; ++oyi) {
                const int ky = ry - oyi;        // compile-time after unroll
                #pragma unroll
                for (int dx = 0; dx < 4; ++dx) {
                    float sacc = 0.f;
                    #pragma unroll
                    for (int kx = 0; kx < 7; ++kx)
                        sacc += wk[ky * 7 + kx] * row[dx + kx];
                    a[oyi][dx] += sacc;
                }
            }
        }
        const float bd = b_dw[c2];
        #pragma unroll
        for (int oyi = 0; oyi < 4; ++oyi) {
            float4 gv = make_float4(fast_gelu(a[oyi][0] + bd), fast_gelu(a[oyi][1] + bd),
                                    fast_gelu(a[oyi][2] + bd), fast_gelu(a[oyi][3] + bd));
            *(float4*)&gbuf[ch * 324 + (ys * 4 + oyi) * 20 + 4 * xq] = gv;
        }
        __syncthreads();

        // ---- fold 16 channels into 32 output accumulators (w_out scalar) ----
        #pragma unroll
        for (int c2l = 0; c2l < 16; ++c2l) {
            float gv = gbuf[c2l * 324 + oy * 20 + ox];
            #pragma unroll
            for (int c = 0; c < 32; ++c)
                acc[c] += w_out[c * C2C + cc * 16 + c2l] * gv;
        }
    }

    #pragma unroll
    for (int c = 0; c < 32; ++c)
        out[((b * C_IN + c) * HH + y0g + oy) * WW + x0g + ox] = acc[c];
}

extern "C" void kernel_launch(void* const* d_in, const int* in_sizes, int n_in,
                              void* d_out, int out_size, void* d_ws, size_t ws_size,
                              hipStream_t stream) {
    const float* x     = (const float*)d_in[0];
    const float* w_in  = (const float*)d_in[1];
    const float* b_in  = (const float*)d_in[2];
    const float* fft1  = (const float*)d_in[3];
    const float* fft2  = (const float*)d_in[4];
    const float* w_dw  = (const float*)d_in[5];
    const float* b_dw  = (const float*)d_in[6];
    const float* w_out = (const float*)d_in[7];
    const float* b_out = (const float*)d_in[8];
    float* outp = (float*)d_out;
    float* z = (float*)d_ws;   // 8*64*256*256 fp32 = 128 MiB intermediate

    dim3 g1(32, 32, 8);
    k1_spectral<<<g1, 512, 0, stream>>>(x, w_in, b_in, fft1, fft2, z);
    dim3 g2(16, 16, 8);
    k2_dwconv<<<g2, 256, 0, stream>>>(z, w_dw, b_dw, w_out, b_out, outp);
}